// Round 6
// baseline (398.209 us; speedup 1.0000x reference)
//
#include <hip/hip_runtime.h>
#include <stdint.h>

typedef _Float16 f16;
typedef _Float16 f16x2 __attribute__((ext_vector_type(2)));
typedef _Float16 f16x4 __attribute__((ext_vector_type(4)));
typedef _Float16 f16x8 __attribute__((ext_vector_type(8)));
typedef float floatx4 __attribute__((ext_vector_type(4)));
typedef float floatx16 __attribute__((ext_vector_type(16)));

#define B_ROWS 4096
#define D_IN   768
#define H_DIM  16384
#define TOPK_N 32
#define NC     40    // target candidate count (superset of exact top-32)
#define NCAP   192   // hard cap on candidates per row

#define BM 256
#define BN 256
#define BK 64
#define NKT (D_IN / BK)   // 12 K-tiles

typedef __attribute__((address_space(1))) const unsigned int g_uint;
typedef __attribute__((address_space(3))) unsigned int l_uint;

__device__ __forceinline__ void gload_lds16(const void* g, void* l) {
    __builtin_amdgcn_global_load_lds((g_uint*)(uintptr_t)g,
                                     (l_uint*)(uint32_t)(uintptr_t)l,
                                     16, 0, 0);
}

// ---------------- split x -> f16 ----------------
__global__ __launch_bounds__(256) void split_x(const float* __restrict__ x,
                                               f16* __restrict__ xhi) {
    const int i = blockIdx.x * 256 + threadIdx.x;
    const float4 q = ((const float4*)x)[i];
    f16x4 h;
    h[0] = (f16)q.x; h[1] = (f16)q.y; h[2] = (f16)q.z; h[3] = (f16)q.w;
    ((f16x4*)xhi)[i] = h;
}

// ---------------- transpose + hi/lo split of W_enc ----------------
// W [768][16384] f32  ->  whiT/wloT [16384][768] f16 (k contiguous)
__global__ __launch_bounds__(256) void split_transpose_w(const float* __restrict__ W,
                                                         f16* __restrict__ whiT,
                                                         f16* __restrict__ wloT) {
    __shared__ float tile[64][65];
    const int kb = blockIdx.x;      // 0..11
    const int nb = blockIdx.y;      // 0..255
    const int t  = threadIdx.x;
    const int col = t & 63;
    const int r4  = t >> 6;
#pragma unroll
    for (int p = 0; p < 16; ++p) {
        const int kr = p * 4 + r4;
        tile[kr][col] = W[(size_t)(kb * 64 + kr) * H_DIM + nb * 64 + col];
    }
    __syncthreads();
    const int n  = t >> 2;
    const int kq = (t & 3) * 16;
    f16x8 h0, h1, l0, l1;
#pragma unroll
    for (int j = 0; j < 8; ++j) {
        const float v0 = tile[kq + j][n];
        const f16 ha = (f16)v0; h0[j] = ha; l0[j] = (f16)(v0 - (float)ha);
        const float v1 = tile[kq + 8 + j][n];
        const f16 hb = (f16)v1; h1[j] = hb; l1[j] = (f16)(v1 - (float)hb);
    }
    const size_t base = (size_t)(nb * 64 + n) * D_IN + kb * 64 + kq;
    *(f16x8*)&whiT[base]     = h0;
    *(f16x8*)&whiT[base + 8] = h1;
    *(f16x8*)&wloT[base]     = l0;
    *(f16x8*)&wloT[base + 8] = l1;
}

// ---------------- encode GEMM: 256x256, BK=64, classic dbuf, 32x32x16 MFMA ----------
// LDS per buffer: A[256][64] f16 (32 KiB) + B[256][64] f16 (32 KiB); 2 buffers = 128 KiB.
// k-slot swizzle: logical 16B-slot s of row r lives at physical slot s ^ (r & 7),
// applied BOTH sides (pre-swizzled global source + swizzled ds_read); LDS dest linear.
// __syncthreads() per K-tile gives RAW+WAR regardless of compiler-emitted VMEM.
// MFMA 32x32x16_f16: A/B per-lane: row/col = lane&31, k-chunk = lane>>5 (8 consecutive k).
// C/D (HW-verified): col = lane&31, row = (r&3) + 8*(r>>2) + 4*(lane>>5), r=0..15.
#define STAGE(buf, kt) do {                                                        \
    const int ko_ = (kt) * BK;                                                     \
    _Pragma("unroll")                                                              \
    for (int q_ = 0; q_ < 4; ++q_)                                                 \
        gload_lds16(xhi + aoff[q_] + ko_, sA + (buf) * 16384 + q_ * 4096 + tid * 8);\
    _Pragma("unroll")                                                              \
    for (int q_ = 0; q_ < 4; ++q_)                                                 \
        gload_lds16(whiT + boff[q_] + ko_, sB + (buf) * 16384 + q_ * 4096 + tid * 8);\
} while (0)

__global__ __launch_bounds__(512, 2) void encode_gemm256(const f16* __restrict__ xhi,
                                                         const f16* __restrict__ whiT,
                                                         const float* __restrict__ b_enc,
                                                         float* __restrict__ preact) {
    extern __shared__ __align__(16) f16 smem[];
    f16* sA = smem;            // 2 * 256 * 64 f16
    f16* sB = smem + 32768;    // 2 * 256 * 64 f16
    const int tid = threadIdx.x;
    const int bid = blockIdx.x;
    const int swz = (bid & 7) * 128 + (bid >> 3);   // XCD swizzle, nwg=1024 % 8 == 0
    const int m0 = (swz >> 6) * BM;                 // 16 m-blocks
    const int n0 = (swz & 63) * BN;                 // 64 n-blocks
    const int lane = tid & 63;
    const int wr = (tid >> 6) >> 2;                 // 0..1
    const int wc = (tid >> 6) & 3;                  // 0..3
    const int lr = lane & 31;                       // row/col within 32
    const int lh = lane >> 5;                       // k-chunk 0..1 (8 consecutive k)

    // staging source offsets (f16 units): thread covers rows q*64 + (tid>>3),
    // 16B chunk c = tid&7, source k-slot pre-swizzled by (row&7) = ((tid>>3)&7)
    const int sw = ((tid & 7) ^ ((tid >> 3) & 7)) << 3;
    int aoff[4], boff[4];
#pragma unroll
    for (int q = 0; q < 4; ++q) {
        const int p = q * 64 + (tid >> 3);
        aoff[q] = (m0 + p) * D_IN + sw;
        boff[q] = (n0 + p) * D_IN + sw;
    }

    floatx16 acc[4][2];
#pragma unroll
    for (int i = 0; i < 4; ++i)
#pragma unroll
        for (int j = 0; j < 2; ++j)
#pragma unroll
            for (int r = 0; r < 16; ++r) acc[i][j][r] = 0.f;

    STAGE(0, 0);
    for (int t = 0; t < NKT; ++t) {
        __syncthreads();                 // drains vmcnt(0)+lgkmcnt(0): tile t landed,
                                         // and iter t-1's ds_reads complete in all waves
        if (t + 1 < NKT) STAGE((t + 1) & 1, t + 1);
        const int bufo = (t & 1) * 16384;
#pragma unroll
        for (int ks = 0; ks < 4; ++ks) {           // 4 k-steps of 16
            const int slog = ks * 2 + lh;          // logical 16B slot (k/8)
            f16x8 af[4], bf[2];
#pragma unroll
            for (int mt = 0; mt < 4; ++mt) {
                const int row = wr * 128 + mt * 32 + lr;
                af[mt] = *(const f16x8*)(sA + bufo + row * 64 + (slog ^ (row & 7)) * 8);
            }
#pragma unroll
            for (int nt = 0; nt < 2; ++nt) {
                const int row = wc * 64 + nt * 32 + lr;
                bf[nt] = *(const f16x8*)(sB + bufo + row * 64 + (slog ^ (row & 7)) * 8);
            }
#pragma unroll
            for (int mt = 0; mt < 4; ++mt)
#pragma unroll
                for (int nt = 0; nt < 2; ++nt)
                    acc[mt][nt] = __builtin_amdgcn_mfma_f32_32x32x16_f16(
                        af[mt], bf[nt], acc[mt][nt], 0, 0, 0);
        }
    }

    // epilogue: 32x32 C/D layout; add bias, fp32 store
#pragma unroll
    for (int nt = 0; nt < 2; ++nt) {
        const int col = n0 + wc * 64 + nt * 32 + lr;
        const float bias = b_enc[col];
#pragma unroll
        for (int mt = 0; mt < 4; ++mt) {
            const int rowb = m0 + wr * 128 + mt * 32 + 4 * lh;
#pragma unroll
            for (int r = 0; r < 16; ++r) {
                const int row = rowb + (r & 3) + 8 * (r >> 2);
                preact[(size_t)row * H_DIM + col] = acc[mt][nt][r] + bias;
            }
        }
    }
}

// ---------------- candidate selection: single-level linear-bin select ----------------
__global__ __launch_bounds__(256) void topk_approx(const float* __restrict__ preact,
                                                   int* __restrict__ cand,
                                                   int* __restrict__ ccnt) {
    const int row = blockIdx.x;
    const int t   = threadIdx.x;
    const float* pr = preact + (size_t)row * H_DIM;
    float vr[64];
    float m = 0.f;
#pragma unroll
    for (int i = 0; i < 16; ++i) {
        const float4 q = ((const float4*)pr)[t + 256 * i];
        vr[4 * i + 0] = q.x; vr[4 * i + 1] = q.y;
        vr[4 * i + 2] = q.z; vr[4 * i + 3] = q.w;
        m = fmaxf(m, fmaxf(fmaxf(q.x, q.y), fmaxf(q.z, q.w)));
    }
#pragma unroll
    for (int off = 32; off > 0; off >>= 1) m = fmaxf(m, __shfl_down(m, off));

    __shared__ float wmax[4];
    __shared__ unsigned hist[256];
    __shared__ unsigned sbin_s, out_cnt;
    if ((t & 63) == 0) wmax[t >> 6] = m;
    hist[t] = 0u;
    if (t == 0) { sbin_s = 0u; out_cnt = 0u; }
    __syncthreads();
    const float M = fmaxf(fmaxf(wmax[0], wmax[1]), fmaxf(wmax[2], wmax[3]));
    int* crow = cand + row * NCAP;

    if (M > 0.f) {
        const float scale = 256.0f / M;
#pragma unroll
        for (int e = 0; e < 64; ++e) {
            const float v = vr[e];
            if (v > 0.f) {
                int b = (int)(v * scale); b = b > 255 ? 255 : b;
                atomicAdd(&hist[b], 1u);
            }
        }
        __syncthreads();
        unsigned sval = hist[t];
        for (int off = 1; off < 256; off <<= 1) {
            const unsigned add = (t + off < 256) ? hist[t + off] : 0u;
            __syncthreads();
            sval += add;
            hist[t] = sval;
            __syncthreads();
        }
        const unsigned above = (t < 255) ? hist[t + 1] : 0u;
        if (sval >= NC && above < NC) sbin_s = (unsigned)t;
        __syncthreads();
        const int sbin = (int)sbin_s;
#pragma unroll
        for (int e = 0; e < 64; ++e) {
            const float v = vr[e];
            if (v > 0.f) {
                int b = (int)(v * scale); b = b > 255 ? 255 : b;
                if (b >= sbin) {
                    const unsigned p = atomicAdd(&out_cnt, 1u);
                    if (p < NCAP) crow[p] = 4 * t + 1024 * (e >> 2) + (e & 3);
                }
            }
        }
        __syncthreads();
    }
    if (t == 0) ccnt[row] = (int)(out_cnt < NCAP ? out_cnt : NCAP);
}

// ---------------- exact fp32 refinement of candidates + hidden write ----------------
__global__ __launch_bounds__(512) void refine_kernel(const float* __restrict__ x,
                                                     const f16* __restrict__ whiT,
                                                     const f16* __restrict__ wloT,
                                                     const float* __restrict__ b_enc,
                                                     const int* __restrict__ cand,
                                                     const int* __restrict__ ccnt,
                                                     float* __restrict__ hidden,
                                                     float* __restrict__ topv,
                                                     int* __restrict__ topi) {
    const int row  = blockIdx.x;
    const int t    = threadIdx.x;
    const int lane = t & 63;
    const int wave = t >> 6;            // 0..7
    __shared__ float xr[D_IN];
    __shared__ float cv[NCAP];
    __shared__ int   ci[NCAP];
    __shared__ float selv[TOPK_N];
    __shared__ int   seli[TOPK_N];

    const int cnt = ccnt[row];
    if (t < NCAP) ci[t] = (t < cnt) ? cand[row * NCAP + t] : -1;
    if (t < TOPK_N) { selv[t] = -3.0e38f; seli[t] = -1; }
    if (t < 512) xr[t] = x[(size_t)row * D_IN + t];
    if (t < D_IN - 512) xr[512 + t] = x[(size_t)row * D_IN + 512 + t];
    __syncthreads();

    for (int c = wave; c < cnt; c += 8) {
        const int n = ci[c];
        float sum = 0.f;
        const f16* wh = whiT + (size_t)n * D_IN;
        const f16* wl = wloT + (size_t)n * D_IN;
#pragma unroll
        for (int j = 0; j < 6; ++j) {
            const int k = 2 * lane + 128 * j;
            const f16x2 h2 = *(const f16x2*)&wh[k];
            const f16x2 l2 = *(const f16x2*)&wl[k];
            const float2 x2 = *(const float2*)&xr[k];
            sum += x2.x * ((float)h2[0] + (float)l2[0]);
            sum += x2.y * ((float)h2[1] + (float)l2[1]);
        }
#pragma unroll
        for (int off = 32; off > 0; off >>= 1) sum += __shfl_down(sum, off);
        if (lane == 0) cv[c] = sum + b_enc[n];
    }
    __syncthreads();

    if (t < cnt) {
        const float vi = cv[t];
        const int   ii = ci[t];
        int rank = 0;
        for (int j = 0; j < cnt; ++j) {
            const float vj = cv[j];
            rank += (vj > vi) || (vj == vi && ci[j] < ii);
        }
        if (rank < TOPK_N) { selv[rank] = vi; seli[rank] = ii; }
    }
    __syncthreads();

    float* hrow = hidden + (size_t)row * H_DIM;
    const float4 z = {0.f, 0.f, 0.f, 0.f};
#pragma unroll
    for (int i = 0; i < 8; ++i) ((float4*)hrow)[t + 512 * i] = z;
    __syncthreads();
    if (t < TOPK_N) {
        const int n = seli[t];
        float v = selv[t];
        v = (n >= 0) ? fmaxf(v, 0.f) : 0.f;
        topv[row * TOPK_N + t] = v;
        topi[row * TOPK_N + t] = (n >= 0) ? n : 0;
        if (v > 0.f) hrow[n] = v;
    }
}

// ---------------- sparse decode: out = relu(hidden_sparse @ W_dec + b_dec) ----------------
// wave-per-row, float4 gather (1024 B/instr coalescing on L3-resident W_dec)
__global__ __launch_bounds__(256) void decode_kernel(const float* __restrict__ topv,
                                                     const int* __restrict__ topi,
                                                     const float* __restrict__ Wdec,
                                                     const float* __restrict__ bdec,
                                                     float* __restrict__ out) {
    const int t = threadIdx.x;
    const int w = t >> 6;
    const int l = t & 63;
    const int row = blockIdx.x * 4 + w;
    __shared__ float sv[4][32];
    __shared__ int   si[4][32];
    if (l < 32) { sv[w][l] = topv[row * TOPK_N + l]; si[w][l] = topi[row * TOPK_N + l]; }
    __syncthreads();
    float4 a0 = {0.f, 0.f, 0.f, 0.f}, a1 = a0, a2 = a0;
#pragma unroll 4
    for (int j = 0; j < TOPK_N; ++j) {
        const float v = sv[w][j];
        const float4* wr = (const float4*)(Wdec + (size_t)si[w][j] * D_IN);
        const float4 q0 = wr[l], q1 = wr[64 + l], q2 = wr[128 + l];
        a0.x += v * q0.x; a0.y += v * q0.y; a0.z += v * q0.z; a0.w += v * q0.w;
        a1.x += v * q1.x; a1.y += v * q1.y; a1.z += v * q1.z; a1.w += v * q1.w;
        a2.x += v * q2.x; a2.y += v * q2.y; a2.z += v * q2.z; a2.w += v * q2.w;
    }
    const float4* b4 = (const float4*)bdec;
    float4* orow = (float4*)(out + (size_t)row * D_IN);
    const float4 b0 = b4[l], b1 = b4[64 + l], b2 = b4[128 + l];
    float4 r0, r1, r2;
    r0.x = fmaxf(a0.x + b0.x, 0.f); r0.y = fmaxf(a0.y + b0.y, 0.f);
    r0.z = fmaxf(a0.z + b0.z, 0.f); r0.w = fmaxf(a0.w + b0.w, 0.f);
    r1.x = fmaxf(a1.x + b1.x, 0.f); r1.y = fmaxf(a1.y + b1.y, 0.f);
    r1.z = fmaxf(a1.z + b1.z, 0.f); r1.w = fmaxf(a1.w + b1.w, 0.f);
    r2.x = fmaxf(a2.x + b2.x, 0.f); r2.y = fmaxf(a2.y + b2.y, 0.f);
    r2.z = fmaxf(a2.z + b2.z, 0.f); r2.w = fmaxf(a2.w + b2.w, 0.f);
    orow[l] = r0; orow[64 + l] = r1; orow[128 + l] = r2;
}

extern "C" void kernel_launch(void* const* d_in, const int* in_sizes, int n_in,
                              void* d_out, int out_size, void* d_ws, size_t ws_size,
                              hipStream_t stream) {
    const float* x     = (const float*)d_in[0];
    const float* W_enc = (const float*)d_in[1];
    const float* b_enc = (const float*)d_in[2];
    const float* W_dec = (const float*)d_in[3];
    const float* b_dec = (const float*)d_in[4];

    float* out    = (float*)d_out;
    float* hidden = out + (size_t)B_ROWS * D_IN;
    float* preact = hidden + (size_t)B_ROWS * H_DIM;

    uint8_t* ws = (uint8_t*)d_ws;
    size_t off = 0;
    f16* xhi  = (f16*)(ws + off); off += (size_t)B_ROWS * D_IN * 2;
    f16* whiT = (f16*)(ws + off); off += (size_t)H_DIM * D_IN * 2;
    f16* wloT = (f16*)(ws + off); off += (size_t)H_DIM * D_IN * 2;
    int*   cand = (int*)(ws + off);  off += (size_t)B_ROWS * NCAP * 4;
    int*   ccnt = (int*)(ws + off);  off += (size_t)B_ROWS * 4;
    float* topv = (float*)(ws + off); off += (size_t)B_ROWS * TOPK_N * 4;
    int*   topi = (int*)(ws + off);  off += (size_t)B_ROWS * TOPK_N * 4;
    if (off > ws_size) return;  // insufficient workspace -> fail visibly

    hipFuncSetAttribute(reinterpret_cast<const void*>(encode_gemm256),
                        hipFuncAttributeMaxDynamicSharedMemorySize, 131072);

    split_x<<<(B_ROWS * D_IN / 4) / 256, 256, 0, stream>>>(x, xhi);
    dim3 gw(D_IN / 64, H_DIM / 64);
    split_transpose_w<<<gw, 256, 0, stream>>>(W_enc, whiT, wloT);
    encode_gemm256<<<(B_ROWS / BM) * (H_DIM / BN), 512, 131072, stream>>>(xhi, whiT, b_enc, preact);
    topk_approx<<<B_ROWS, 256, 0, stream>>>(preact, cand, ccnt);
    refine_kernel<<<B_ROWS, 512, 0, stream>>>(x, whiT, wloT, b_enc, cand, ccnt, hidden, topv, topi);
    decode_kernel<<<B_ROWS / 4, 256, 0, stream>>>(topv, topi, W_dec, b_dec, out);
}